// Round 1
// baseline (232.373 us; speedup 1.0000x reference)
//
#include <hip/hip_runtime.h>

#define BB 4
#define NN 1024
#define KK 9
#define C  32
#define CM 128
#define M  (BB*NN)       // 4096 rows
#define EPSB 1e-5f
#define SLOPE 0.01f

__device__ __forceinline__ float leaky(float x){ return x > 0.f ? x : SLOPE*x; }

// ---------------------------------------------------------------------------
// K1: comp_w[b,n,k,d] = sum_c w[b,n,c] * conv_w[k,c,d]
// grid 64 blocks x 256 thr; block handles 64 rows
// ---------------------------------------------------------------------------
__global__ __launch_bounds__(256) void k1_compw(const float* __restrict__ w,
                                                const float* __restrict__ conv_w,
                                                float* __restrict__ comp_w){
  __shared__ float cw[KK*C*C];   // 36 KB
  __shared__ float wl[64*C];     // 8 KB
  int row0 = blockIdx.x * 64;
  for (int i = threadIdx.x; i < KK*C*C; i += 256) cw[i] = conv_w[i];
  for (int i = threadIdx.x; i < 64*C;   i += 256) wl[i] = w[(size_t)row0*C + i];
  __syncthreads();
  for (int o = threadIdx.x; o < 64*KK*C; o += 256){
    int nl  = o / (KK*C);
    int rem = o % (KK*C);
    int k = rem / C, d = rem % C;
    float acc = 0.f;
    const float* wp = &wl[nl*C];
    const float* cp = &cw[k*C*C + d];
    #pragma unroll
    for (int c = 0; c < C; ++c) acc += wp[c] * cp[c*C];
    comp_w[(size_t)(row0+nl)*KK*C + rem] = acc;
  }
}

// ---------------------------------------------------------------------------
// K2: main Gaussian-mixture evaluation, split over n into S chunks.
// grid = B*2*S blocks x 256 thr. Each thread: 8 i's x 8 channels (64 acc).
// part[(nc*M + row)*C + c] = partial sum over this block's n-chunk.
// ---------------------------------------------------------------------------
__global__ __launch_bounds__(256) void k2_main(const float* __restrict__ pos,
                                               const float* __restrict__ kpos,
                                               const float* __restrict__ comp_w,
                                               float* __restrict__ part,
                                               int S, int NCH){
  extern __shared__ float lds[];
  float* cwl = lds;                 // NCH*288 floats
  float* pnl = lds + NCH*KK*C;      // NCH*2 floats
  int bid = blockIdx.x;
  int nc = bid % S;
  int it = (bid / S) & 1;
  int b  = bid / (S*2);
  int tid = threadIdx.x;
  int cg = tid & 3, ig = tid >> 2;        // 4 channel groups x 64 i-groups
  int i0 = it*512 + ig*8;
  int c0 = cg*8;

  float kx[KK], ky[KK];
  #pragma unroll
  for (int k = 0; k < KK; ++k){ kx[k] = kpos[2*k]; ky[k] = kpos[2*k+1]; }

  float px[8], py[8];
  #pragma unroll
  for (int ii = 0; ii < 8; ++ii){
    int row = b*NN + i0 + ii;
    px[ii] = pos[2*row]; py[ii] = pos[2*row+1];
  }

  int n0 = nc*NCH;
  const float4* src = (const float4*)(comp_w + (size_t)(b*NN + n0)*KK*C);
  float4* dst = (float4*)cwl;
  int nv = NCH*KK*C/4;
  for (int v = tid; v < nv; v += 256) dst[v] = src[v];
  for (int v = tid; v < NCH*2; v += 256) pnl[v] = pos[(size_t)(b*NN+n0)*2 + v];
  __syncthreads();

  float acc[8][8];
  #pragma unroll
  for (int ii=0;ii<8;++ii)
    #pragma unroll
    for (int c=0;c<8;++c) acc[ii][c]=0.f;

  for (int n = 0; n < NCH; ++n){
    float pnx = pnl[2*n], pny = pnl[2*n+1];
    float dx[8], dy[8];
    #pragma unroll
    for (int ii=0;ii<8;++ii){ dx[ii]=px[ii]-pnx; dy[ii]=py[ii]-pny; }
    #pragma unroll
    for (int k = 0; k < KK; ++k){
      float4 ca = *(const float4*)&cwl[(n*KK+k)*C + c0];
      float4 cb = *(const float4*)&cwl[(n*KK+k)*C + c0 + 4];
      #pragma unroll
      for (int ii=0;ii<8;++ii){
        float ddx = dx[ii]-kx[k], ddy = dy[ii]-ky[k];
        float e = __expf(-0.5f*(ddx*ddx + ddy*ddy));
        acc[ii][0] += e*ca.x; acc[ii][1] += e*ca.y;
        acc[ii][2] += e*ca.z; acc[ii][3] += e*ca.w;
        acc[ii][4] += e*cb.x; acc[ii][5] += e*cb.y;
        acc[ii][6] += e*cb.z; acc[ii][7] += e*cb.w;
      }
    }
  }
  #pragma unroll
  for (int ii=0;ii<8;++ii){
    size_t idx = ((size_t)nc*M + (size_t)b*NN + i0 + ii)*C + c0;
    float4 o1 = {acc[ii][0],acc[ii][1],acc[ii][2],acc[ii][3]};
    float4 o2 = {acc[ii][4],acc[ii][5],acc[ii][6],acc[ii][7]};
    *(float4*)&part[idx]   = o1;
    *(float4*)&part[idx+4] = o2;
  }
}

// ---------------------------------------------------------------------------
// K3: z = leaky(sum_s part) ; accumulate per-channel sum/sumsq (stats[0..63])
// grid 512 x 256, one element each
// ---------------------------------------------------------------------------
__global__ __launch_bounds__(256) void k3_reduce(const float* __restrict__ part,
                                                 float* __restrict__ z,
                                                 float* __restrict__ stats,
                                                 int S){
  __shared__ float ls1[C], ls2[C];
  int tid = threadIdx.x;
  if (tid < C){ ls1[tid]=0.f; ls2[tid]=0.f; }
  __syncthreads();
  size_t idx = (size_t)blockIdx.x*256 + tid;
  float s = 0.f;
  for (int p = 0; p < S; ++p) s += part[(size_t)p*M*C + idx];
  s = leaky(s);
  z[idx] = s;
  atomicAdd(&ls1[tid & (C-1)], s);
  atomicAdd(&ls2[tid & (C-1)], s*s);
  __syncthreads();
  if (tid < C){ atomicAdd(&stats[tid], ls1[tid]); atomicAdd(&stats[C+tid], ls2[tid]); }
}

// ---------------------------------------------------------------------------
// K4: y = bn(z)+weights ; h = leaky(y@w1+b1) ; stats for h (stats[64..319])
// grid M/16 x 256; block handles 16 rows
// ---------------------------------------------------------------------------
__global__ __launch_bounds__(256) void k4_mlp1(const float* __restrict__ z,
                                               const float* __restrict__ weights,
                                               const float* __restrict__ bn_g,
                                               const float* __restrict__ bn_b,
                                               const float* __restrict__ w1,
                                               const float* __restrict__ b1,
                                               float* __restrict__ stats,
                                               float* __restrict__ y,
                                               float* __restrict__ h){
  __shared__ float w1l[C*CM];   // 16 KB
  __shared__ float yl[16*C];
  __shared__ float lt1[CM], lt2[CM];
  int tid = threadIdx.x;
  int row0 = blockIdx.x * 16;
  for (int i = tid; i < C*CM; i += 256) w1l[i] = w1[i];
  if (tid < CM){ lt1[tid]=0.f; lt2[tid]=0.f; }
  #pragma unroll
  for (int j = 0; j < 2; ++j){
    int e = tid + j*256;
    int c  = e & (C-1);
    int rl = e >> 5;
    float s1 = stats[c], s2 = stats[C + c];
    float mean = s1 * (1.f/M);
    float var  = s2 * (1.f/M) - mean*mean;
    float sc = bn_g[c] * rsqrtf(var + EPSB);
    float sh = bn_b[c] - mean*sc;
    int row = row0 + rl;
    float v = z[(size_t)row*C + c]*sc + sh + weights[(size_t)row*C + c];
    yl[e] = v;
    y[(size_t)row*C + c] = v;
  }
  __syncthreads();
  #pragma unroll
  for (int j = 0; j < 8; ++j){
    int e = tid + j*256;
    int col = e & (CM-1);
    int rl  = e >> 7;
    float acc = b1[col];
    #pragma unroll
    for (int c = 0; c < C; ++c) acc += yl[rl*C + c] * w1l[c*CM + col];
    acc = leaky(acc);
    h[(size_t)(row0+rl)*CM + col] = acc;
    atomicAdd(&lt1[col], acc);
    atomicAdd(&lt2[col], acc*acc);
  }
  __syncthreads();
  if (tid < CM){
    atomicAdd(&stats[2*C + tid],      lt1[tid]);
    atomicAdd(&stats[2*C + CM + tid], lt2[tid]);
  }
}

// ---------------------------------------------------------------------------
// K5: out = y + (bn1(h) @ w2 + b2)
// grid M/16 x 256
// ---------------------------------------------------------------------------
__global__ __launch_bounds__(256) void k5_mlp2(const float* __restrict__ h,
                                               const float* __restrict__ y,
                                               const float* __restrict__ bn1_g,
                                               const float* __restrict__ bn1_b,
                                               const float* __restrict__ w2,
                                               const float* __restrict__ b2,
                                               const float* __restrict__ stats,
                                               float* __restrict__ out){
  __shared__ float w2l[CM*C];   // 16 KB
  __shared__ float hl[16*CM];   // 8 KB
  int tid = threadIdx.x;
  int row0 = blockIdx.x * 16;
  for (int i = tid; i < CM*C; i += 256) w2l[i] = w2[i];
  #pragma unroll
  for (int j = 0; j < 8; ++j){
    int e = tid + j*256;
    int col = e & (CM-1);
    int rl  = e >> 7;
    float t1 = stats[2*C + col], t2 = stats[2*C + CM + col];
    float mean = t1*(1.f/M);
    float var  = t2*(1.f/M) - mean*mean;
    float sc = bn1_g[col]*rsqrtf(var + EPSB);
    float sh = bn1_b[col] - mean*sc;
    hl[e] = h[(size_t)(row0+rl)*CM + col]*sc + sh;
  }
  __syncthreads();
  #pragma unroll
  for (int j = 0; j < 2; ++j){
    int e = tid + j*256;
    int c  = e & (C-1);
    int rl = e >> 5;
    float acc = b2[c];
    #pragma unroll
    for (int jj = 0; jj < CM; ++jj) acc += hl[rl*CM + jj] * w2l[jj*C + c];
    int row = row0 + rl;
    out[(size_t)row*C + c] = y[(size_t)row*C + c] + acc;
  }
}

// ---------------------------------------------------------------------------
extern "C" void kernel_launch(void* const* d_in, const int* in_sizes, int n_in,
                              void* d_out, int out_size, void* d_ws, size_t ws_size,
                              hipStream_t stream) {
  const float* positions = (const float*)d_in[0];
  const float* weights   = (const float*)d_in[1];
  const float* kpos      = (const float*)d_in[2];
  const float* conv_w    = (const float*)d_in[3];
  const float* bn_g      = (const float*)d_in[4];
  const float* bn_b      = (const float*)d_in[5];
  const float* w1        = (const float*)d_in[6];
  const float* b1        = (const float*)d_in[7];
  const float* bn1_g     = (const float*)d_in[8];
  const float* bn1_b     = (const float*)d_in[9];
  const float* w2        = (const float*)d_in[10];
  const float* b2        = (const float*)d_in[11];
  float* out = (float*)d_out;

  float* ws = (float*)d_ws;
  size_t off = 0;
  float* comp_w = ws + off; off += (size_t)M*KK*C;             // 1,179,648 floats
  size_t fixed = off + (size_t)M*C + (size_t)M*C + (size_t)M*CM + 320;
  int S = 64;
  while (S > 8 && (fixed + (size_t)S*M*C)*4 > ws_size) S >>= 1;
  float* part  = ws + off; off += (size_t)S*M*C;
  float* z     = ws + off; off += (size_t)M*C;
  float* y     = ws + off; off += (size_t)M*C;
  float* h     = ws + off; off += (size_t)M*CM;
  float* stats = ws + off; off += 320;

  hipMemsetAsync(stats, 0, 320*sizeof(float), stream);
  k1_compw<<<M/64, 256, 0, stream>>>(weights, conv_w, comp_w);
  int NCH = NN / S;
  int smem = (NCH*KK*C + NCH*2) * (int)sizeof(float);
  k2_main<<<BB*2*S, 256, smem, stream>>>(positions, kpos, comp_w, part, S, NCH);
  k3_reduce<<<(M*C)/256, 256, 0, stream>>>(part, z, stats, S);
  k4_mlp1<<<M/16, 256, 0, stream>>>(z, weights, bn_g, bn_b, w1, b1, stats, y, h);
  k5_mlp2<<<M/16, 256, 0, stream>>>(h, y, bn1_g, bn1_b, w2, b2, stats, out);
}

// Round 2
// 146.879 us; speedup vs baseline: 1.5821x; 1.5821x over previous
//
#include <hip/hip_runtime.h>

#define BB 4
#define NN 1024
#define KK 9
#define C  32
#define CM 128
#define M  (BB*NN)       // 4096 rows
#define EPSB 1e-5f
#define SLOPE 0.01f

#define SCH 4            // n-chunks (part slots)
#define NCH 256          // n per chunk
#define NSUB 32          // n per sub-chunk
#define KDIM 288         // NSUB*KK, MFMA K per sub-chunk
#define KPAD 296         // padded row stride (f16) for LDS/global comp_w tiles
#define CHUNK_F16 (32*KPAD)   // 9472 f16 per (b,nc,sub) tile

typedef _Float16 f16x8 __attribute__((ext_vector_type(8)));
typedef _Float16 f16x4 __attribute__((ext_vector_type(4)));
typedef float    f32x4 __attribute__((ext_vector_type(4)));

__device__ __forceinline__ float leaky(float x){ return x > 0.f ? x : SLOPE*x; }

// ---------------------------------------------------------------------------
// K1: comp_w_h[((b*4+nc)*8+sub)][c][k*32+nl] (f16, row stride KPAD)
//      = sum_c' w[row][c'] * conv_w[k][c'][c],  row = ((b*4+nc)*8+sub)*32+nl
// grid 384 = (b,nc,sub) x kt(3 k's each); thread = (nl 32) x (dq 8: 4 d each)
// Block 0 also zeroes the stats buffer (replaces hipMemsetAsync).
// ---------------------------------------------------------------------------
__global__ __launch_bounds__(256) void k1_compw(const float* __restrict__ w,
                                                const float* __restrict__ conv_w,
                                                _Float16* __restrict__ cwh,
                                                float* __restrict__ stats){
  __shared__ float cwl[3*C*C];   // 12 KB: conv_w k-slice
  int bid = blockIdx.x;
  int kt  = bid % 3;
  int sub = (bid/3)&7, nc = (bid/24)&3, b = bid/96;
  int tid = threadIdx.x;
  if (bid == 0){ for (int i = tid; i < 320; i += 256) stats[i] = 0.f; }

  const float4* cs = (const float4*)(conv_w + kt*3*C*C);
  float4* cd = (float4*)cwl;
  for (int v = tid; v < 768; v += 256) cd[v] = cs[v];

  int nl = tid & 31, dq = tid >> 5;
  int row = ((b*4 + nc)*8 + sub)*32 + nl;
  float wreg[32];
  const float4* wr = (const float4*)(w + (size_t)row*C);
  #pragma unroll
  for (int j = 0; j < 8; ++j){
    float4 t = wr[j];
    wreg[4*j]=t.x; wreg[4*j+1]=t.y; wreg[4*j+2]=t.z; wreg[4*j+3]=t.w;
  }
  __syncthreads();

  _Float16* outb = cwh + (size_t)((b*4+nc)*8 + sub)*CHUNK_F16;
  const float4* cv = (const float4*)cwl;
  #pragma unroll
  for (int kl = 0; kl < 3; ++kl){
    float a0=0.f, a1=0.f, a2=0.f, a3=0.f;
    #pragma unroll
    for (int c = 0; c < C; ++c){
      float4 t = cv[kl*256 + c*8 + dq];   // conv_w[kt*3+kl][c][dq*4..+3], broadcast
      a0 += wreg[c]*t.x; a1 += wreg[c]*t.y; a2 += wreg[c]*t.z; a3 += wreg[c]*t.w;
    }
    int k = kt*3 + kl;
    outb[(dq*4+0)*KPAD + k*32 + nl] = (_Float16)a0;
    outb[(dq*4+1)*KPAD + k*32 + nl] = (_Float16)a1;
    outb[(dq*4+2)*KPAD + k*32 + nl] = (_Float16)a2;
    outb[(dq*4+3)*KPAD + k*32 + nl] = (_Float16)a3;
  }
}

// ---------------------------------------------------------------------------
// K2: flash-style MFMA. Block = (b, it: 32-i tile, nc: 256-n chunk), 4 waves.
// Per sub-chunk (32 n): stage comp_w f16 tile, VALU-gen kmat f16 tile,
// then each wave does 9 x mfma_f32_16x16x32_f16 into its 16x16 (i,c) tile.
// part[(nc*M + row)*C + c] = partial over this block's n-chunk.
// ---------------------------------------------------------------------------
__global__ __launch_bounds__(256) void k2_main(const float* __restrict__ pos,
                                               const float* __restrict__ kpos,
                                               const _Float16* __restrict__ cwh,
                                               float* __restrict__ part){
  __shared__ _Float16 km[32*KPAD];   // 18944 B: kmat tile [i][K]
  __shared__ _Float16 cw[32*KPAD];   // 18944 B: comp_w tile [c][K]
  __shared__ float pnl[NCH*2];       // 2 KB
  int bid = blockIdx.x;
  int nc = bid & 3, it = (bid>>2)&31, b = bid>>7;
  int tid = threadIdx.x;
  int lane = tid & 63, wid = tid >> 6;
  int i0 = (wid>>1)*16, c0 = (wid&1)*16;
  int mm = lane & 15, quad = lane >> 4;

  const float* pbase = pos + (size_t)(b*NN + nc*NCH)*2;
  for (int v = tid; v < NCH*2; v += 256) pnl[v] = pbase[v];

  int ig = tid >> 3, np = tid & 7;      // gen role: row ig, n-quad np
  float pix = pos[(size_t)(b*NN + it*32 + ig)*2];
  float piy = pos[(size_t)(b*NN + it*32 + ig)*2 + 1];
  float kx[KK], ky[KK];
  #pragma unroll
  for (int k = 0; k < KK; ++k){ kx[k] = kpos[2*k]; ky[k] = kpos[2*k+1]; }

  f32x4 acc = {0.f,0.f,0.f,0.f};
  __syncthreads();

  for (int s = 0; s < 8; ++s){
    // stage comp_w tile (layout matches global exactly; straight memcpy)
    const float4* srcs = (const float4*)(cwh + (size_t)((b*4+nc)*8 + s)*CHUNK_F16);
    float4* dst = (float4*)cw;
    for (int v = tid; v < CHUNK_F16/8; v += 256) dst[v] = srcs[v];

    // generate kmat tile: 36 exps/thread
    float dx[4], dy[4];
    #pragma unroll
    for (int jj = 0; jj < 4; ++jj){
      int nl = np*4 + jj;
      dx[jj] = pix - pnl[2*(s*32+nl)];
      dy[jj] = piy - pnl[2*(s*32+nl)+1];
    }
    #pragma unroll
    for (int k = 0; k < KK; ++k){
      f16x4 ev;
      #pragma unroll
      for (int jj = 0; jj < 4; ++jj){
        float ddx = dx[jj]-kx[k], ddy = dy[jj]-ky[k];
        ev[jj] = (_Float16)__expf(-0.5f*(ddx*ddx + ddy*ddy));
      }
      *(f16x4*)&km[ig*KPAD + k*32 + np*4] = ev;
    }
    __syncthreads();

    #pragma unroll
    for (int ks = 0; ks < 9; ++ks){
      f16x8 a  = *(const f16x8*)&km[(i0+mm)*KPAD + ks*32 + quad*8];
      f16x8 bf = *(const f16x8*)&cw[(c0+mm)*KPAD + ks*32 + quad*8];
      acc = __builtin_amdgcn_mfma_f32_16x16x32_f16(a, bf, acc, 0, 0, 0);
    }
    __syncthreads();
  }

  int grow0 = b*NN + it*32 + i0;
  #pragma unroll
  for (int r = 0; r < 4; ++r){
    int grow = grow0 + quad*4 + r;
    part[((size_t)nc*M + grow)*C + c0 + mm] = acc[r];
  }
}

// ---------------------------------------------------------------------------
// K3: z = leaky(sum_s part) ; per-channel sum/sumsq into stats[0..63]
// ---------------------------------------------------------------------------
__global__ __launch_bounds__(256) void k3_reduce(const float* __restrict__ part,
                                                 float* __restrict__ z,
                                                 float* __restrict__ stats,
                                                 int S){
  __shared__ float ls1[C], ls2[C];
  int tid = threadIdx.x;
  if (tid < C){ ls1[tid]=0.f; ls2[tid]=0.f; }
  __syncthreads();
  size_t idx = (size_t)blockIdx.x*256 + tid;
  float s = 0.f;
  for (int p = 0; p < S; ++p) s += part[(size_t)p*M*C + idx];
  s = leaky(s);
  z[idx] = s;
  atomicAdd(&ls1[tid & (C-1)], s);
  atomicAdd(&ls2[tid & (C-1)], s*s);
  __syncthreads();
  if (tid < C){ atomicAdd(&stats[tid], ls1[tid]); atomicAdd(&stats[C+tid], ls2[tid]); }
}

// ---------------------------------------------------------------------------
// K4: y = bn(z)+weights ; h = leaky(y@w1+b1) ; stats for h (stats[64..319])
// ---------------------------------------------------------------------------
__global__ __launch_bounds__(256) void k4_mlp1(const float* __restrict__ z,
                                               const float* __restrict__ weights,
                                               const float* __restrict__ bn_g,
                                               const float* __restrict__ bn_b,
                                               const float* __restrict__ w1,
                                               const float* __restrict__ b1,
                                               float* __restrict__ stats,
                                               float* __restrict__ y,
                                               float* __restrict__ h){
  __shared__ float w1l[C*CM];   // 16 KB
  __shared__ float yl[16*C];
  __shared__ float lt1[CM], lt2[CM];
  int tid = threadIdx.x;
  int row0 = blockIdx.x * 16;
  for (int i = tid; i < C*CM; i += 256) w1l[i] = w1[i];
  if (tid < CM){ lt1[tid]=0.f; lt2[tid]=0.f; }
  #pragma unroll
  for (int j = 0; j < 2; ++j){
    int e = tid + j*256;
    int c  = e & (C-1);
    int rl = e >> 5;
    float s1 = stats[c], s2 = stats[C + c];
    float mean = s1 * (1.f/M);
    float var  = s2 * (1.f/M) - mean*mean;
    float sc = bn_g[c] * rsqrtf(var + EPSB);
    float sh = bn_b[c] - mean*sc;
    int row = row0 + rl;
    float v = z[(size_t)row*C + c]*sc + sh + weights[(size_t)row*C + c];
    yl[e] = v;
    y[(size_t)row*C + c] = v;
  }
  __syncthreads();
  #pragma unroll
  for (int j = 0; j < 8; ++j){
    int e = tid + j*256;
    int col = e & (CM-1);
    int rl  = e >> 7;
    float acc = b1[col];
    #pragma unroll
    for (int c = 0; c < C; ++c) acc += yl[rl*C + c] * w1l[c*CM + col];
    acc = leaky(acc);
    h[(size_t)(row0+rl)*CM + col] = acc;
    atomicAdd(&lt1[col], acc);
    atomicAdd(&lt2[col], acc*acc);
  }
  __syncthreads();
  if (tid < CM){
    atomicAdd(&stats[2*C + tid],      lt1[tid]);
    atomicAdd(&stats[2*C + CM + tid], lt2[tid]);
  }
}

// ---------------------------------------------------------------------------
// K5: out = y + (bn1(h) @ w2 + b2)
// ---------------------------------------------------------------------------
__global__ __launch_bounds__(256) void k5_mlp2(const float* __restrict__ h,
                                               const float* __restrict__ y,
                                               const float* __restrict__ bn1_g,
                                               const float* __restrict__ bn1_b,
                                               const float* __restrict__ w2,
                                               const float* __restrict__ b2,
                                               const float* __restrict__ stats,
                                               float* __restrict__ out){
  __shared__ float w2l[CM*C];   // 16 KB
  __shared__ float hl[16*CM];   // 8 KB
  int tid = threadIdx.x;
  int row0 = blockIdx.x * 16;
  for (int i = tid; i < CM*C; i += 256) w2l[i] = w2[i];
  #pragma unroll
  for (int j = 0; j < 8; ++j){
    int e = tid + j*256;
    int col = e & (CM-1);
    int rl  = e >> 7;
    float t1 = stats[2*C + col], t2 = stats[2*C + CM + col];
    float mean = t1*(1.f/M);
    float var  = t2*(1.f/M) - mean*mean;
    float sc = bn1_g[col]*rsqrtf(var + EPSB);
    float sh = bn1_b[col] - mean*sc;
    hl[e] = h[(size_t)(row0+rl)*CM + col]*sc + sh;
  }
  __syncthreads();
  #pragma unroll
  for (int j = 0; j < 2; ++j){
    int e = tid + j*256;
    int c  = e & (C-1);
    int rl = e >> 5;
    float acc = b2[c];
    #pragma unroll
    for (int jj = 0; jj < CM; ++jj) acc += hl[rl*CM + jj] * w2l[jj*C + c];
    int row = row0 + rl;
    out[(size_t)row*C + c] = y[(size_t)row*C + c] + acc;
  }
}

// ---------------------------------------------------------------------------
extern "C" void kernel_launch(void* const* d_in, const int* in_sizes, int n_in,
                              void* d_out, int out_size, void* d_ws, size_t ws_size,
                              hipStream_t stream) {
  const float* positions = (const float*)d_in[0];
  const float* weights   = (const float*)d_in[1];
  const float* kpos      = (const float*)d_in[2];
  const float* conv_w    = (const float*)d_in[3];
  const float* bn_g      = (const float*)d_in[4];
  const float* bn_b      = (const float*)d_in[5];
  const float* w1        = (const float*)d_in[6];
  const float* b1        = (const float*)d_in[7];
  const float* bn1_g     = (const float*)d_in[8];
  const float* bn1_b     = (const float*)d_in[9];
  const float* w2        = (const float*)d_in[10];
  const float* b2        = (const float*)d_in[11];
  float* out = (float*)d_out;

  float* ws = (float*)d_ws;
  size_t off = 0;
  _Float16* cwh = (_Float16*)(ws + off); off += (size_t)128*CHUNK_F16/2;  // 606,208 floats
  float* part  = ws + off; off += (size_t)SCH*M*C;
  float* z     = ws + off; off += (size_t)M*C;
  float* y     = ws + off; off += (size_t)M*C;
  float* h     = ws + off; off += (size_t)M*CM;
  float* stats = ws + off; off += 320;

  k1_compw<<<384, 256, 0, stream>>>(weights, conv_w, cwh, stats);
  k2_main <<<512, 256, 0, stream>>>(positions, kpos, cwh, part);
  k3_reduce<<<(M*C)/256, 256, 0, stream>>>(part, z, stats, SCH);
  k4_mlp1<<<M/16, 256, 0, stream>>>(z, weights, bn_g, bn_b, w1, b1, stats, y, h);
  k5_mlp2<<<M/16, 256, 0, stream>>>(h, y, bn1_g, bn1_b, w2, b2, stats, out);
}